// Round 1
// baseline (2110.295 us; speedup 1.0000x reference)
//
#include <hip/hip_runtime.h>
#include <hip/hip_bf16.h>
#include <stdint.h>

#define NB 64
#define NN 1024
#define NH 128
#define NS 12
#define BN (NB*NN)
#define D0 129
#define K0P 416
#define K1 768
#define NG 512
#define MAXNNZ 128

typedef __hip_bfloat16 bf16;
typedef float v4f __attribute__((ext_vector_type(4)));
typedef __bf16 v8bf __attribute__((ext_vector_type(8)));

__device__ __forceinline__ float bf2f(bf16 x) { return __bfloat162float(x); }
__device__ __forceinline__ bf16 f2bf(float x) { return __float2bfloat16(x); }
__device__ __forceinline__ float sane(float x) { return __builtin_isfinite(x) ? x : 0.f; }
__device__ __forceinline__ float sigf(float x) { return 1.f / (1.f + __expf(-x)); }
__device__ __forceinline__ float tanhfast(float x) { return 1.f - 2.f / (1.f + __expf(2.f * x)); }

// flagged load/store: f32 ? float data : bf16 data (flag is uniform per launch)
__device__ __forceinline__ float loadF(const void* p, size_t i, int f32) {
  return f32 ? ((const float*)p)[i] : bf2f(((const bf16*)p)[i]);
}
__device__ __forceinline__ void storeF(void* p, size_t i, float v, int f32) {
  if (f32) ((float*)p)[i] = v; else ((bf16*)p)[i] = f2bf(v);
}
// 8 elements -> v8bf; f32 path uses two float4 loads + packed converts
__device__ __forceinline__ v8bf load8(const void* p, size_t i, int f32) {
  if (f32) {
    const float4 a = *(const float4*)((const float*)p + i);
    const float4 b = *(const float4*)((const float*)p + i + 4);
    union { v8bf v; __hip_bfloat162 h[4]; } u;
    u.h[0] = __float22bfloat162_rn(make_float2(a.x, a.y));
    u.h[1] = __float22bfloat162_rn(make_float2(a.z, a.w));
    u.h[2] = __float22bfloat162_rn(make_float2(b.x, b.y));
    u.h[3] = __float22bfloat162_rn(make_float2(b.z, b.w));
    return u.v;
  }
  return *(const v8bf*)((const bf16*)p + i);
}

// dtype detector on ~N(0,1) probe: bf16 data -> even uint16s are real bf16
// (exponent 117..131 or zero); f32 data -> even uint16s are mantissa halves.
__global__ void detect_dtype(const unsigned short* __restrict__ probe, int* __restrict__ flag) {
  int t = threadIdx.x;
  unsigned short x = probe[2 * t];
  int e = (x >> 7) & 0xFF;
  int insane = !((x & 0x7FFF) == 0 || (e >= 117 && e <= 131));
  __shared__ int cnt;
  if (t == 0) cnt = 0;
  __syncthreads();
  atomicAdd(&cnt, insane);
  __syncthreads();
  if (t == 0) *flag = (cnt > 64) ? 1 : 0;
}

__global__ void build_csr(const void* __restrict__ sup, int* __restrict__ cols,
                          float* __restrict__ vals, int* __restrict__ cnt,
                          const int* __restrict__ flag) {
  int f32 = *flag;
  int n = blockIdx.x;
  __shared__ int cn;
  if (threadIdx.x == 0) cn = 0;
  __syncthreads();
  for (int m = threadIdx.x; m < NN; m += blockDim.x) {
    float v = loadF(sup, (size_t)n * NN + m, f32);
    if (v != 0.0f && __builtin_isfinite(v)) {
      int slot = atomicAdd(&cn, 1);
      if (slot < MAXNNZ) { cols[n * MAXNNZ + slot] = m; vals[n * MAXNNZ + slot] = v; }
    }
  }
  __syncthreads();
  if (threadIdx.x == 0) cnt[n] = (cn < MAXNNZ) ? cn : MAXNNZ;
}

__global__ void pack_wt(const void* __restrict__ w, bf16* __restrict__ bt,
                        int K, int Kp, int Nn, const int* __restrict__ flag) {
  int f32 = *flag;
  int n = blockIdx.x;
  for (int k = threadIdx.x; k < Kp; k += blockDim.x) {
    float v = (k < K) ? loadF(w, (size_t)k * Nn + n, f32) : 0.0f;
    bt[(size_t)n * Kp + k] = f2bf(v);
  }
}

// ---- layer 0 diffusion (whole problem; no chunking) ----
__global__ void diffuse0_a(const void* __restrict__ xin, const void* __restrict__ h0,
                           const int* __restrict__ cols, const float* __restrict__ vals,
                           const int* __restrict__ cnt, bf16* __restrict__ feats,
                           const int* __restrict__ flag) {
  int f32 = *flag;
  int bn = blockIdx.x;
  int n = bn & (NN - 1);
  int b = bn >> 10;
  int d = threadIdx.x;
  bf16* frow = feats + (size_t)bn * K0P;
  if (d < D0) {
    float x0 = (d == 0) ? loadF(xin, bn, f32) : loadF(h0, (size_t)bn * NH + d - 1, f32);
    frow[d] = f2bf(x0);
    float acc = 0.f;
    int c = cnt[n];
    for (int j = 0; j < c; ++j) {
      int m = cols[n * MAXNNZ + j];
      float s = vals[n * MAXNNZ + j];
      int bm = (b << 10) | m;
      float xv = (d == 0) ? loadF(xin, bm, f32) : loadF(h0, (size_t)bm * NH + d - 1, f32);
      acc += s * xv;
    }
    frow[D0 + d] = f2bf(acc);
  } else if (d < D0 + (K0P - 3 * D0)) {
    frow[3 * D0 + (d - D0)] = f2bf(0.f);
  }
}

__global__ void diffuse0_b(const void* __restrict__ xin, const void* __restrict__ h0,
                           const int* __restrict__ cols, const float* __restrict__ vals,
                           const int* __restrict__ cnt, bf16* __restrict__ feats,
                           const int* __restrict__ flag) {
  int f32 = *flag;
  int bn = blockIdx.x;
  int n = bn & (NN - 1);
  int b = bn >> 10;
  int d = threadIdx.x;
  if (d >= D0) return;
  float x0 = (d == 0) ? loadF(xin, bn, f32) : loadF(h0, (size_t)bn * NH + d - 1, f32);
  float acc = -x0;
  int c = cnt[n];
  for (int j = 0; j < c; ++j) {
    int m = cols[n * MAXNNZ + j];
    float s = vals[n * MAXNNZ + j];
    int bm = (b << 10) | m;
    float x1 = bf2f(feats[(size_t)bm * K0P + D0 + d]);
    acc += 2.f * s * x1;
  }
  feats[(size_t)bn * K0P + 2 * D0 + d] = f2bf(acc);
}

// ---- layer 1 diffusion ----
__global__ void diffuse1_a(const void* __restrict__ dout, size_t offH0,
                           const void* __restrict__ hidden, size_t offH1in,
                           const int* __restrict__ cols, const float* __restrict__ vals,
                           const int* __restrict__ cnt, bf16* __restrict__ feats,
                           const int* __restrict__ flag) {
  int f32 = *flag;
  int bn = blockIdx.x;
  int n = bn & (NN - 1);
  int b = bn >> 10;
  int d = threadIdx.x;   // 0..255
  bf16* frow = feats + (size_t)bn * K1;
  float x0 = (d < NH) ? loadF(dout, offH0 + (size_t)bn * NH + d, f32)
                      : loadF(hidden, offH1in + (size_t)bn * NH + d - NH, f32);
  frow[d] = f2bf(x0);
  float acc = 0.f;
  int c = cnt[n];
  for (int j = 0; j < c; ++j) {
    int m = cols[n * MAXNNZ + j];
    float s = vals[n * MAXNNZ + j];
    size_t bm = (size_t)((b << 10) | m) * NH;
    float xv = (d < NH) ? loadF(dout, offH0 + bm + d, f32)
                        : loadF(hidden, offH1in + bm + d - NH, f32);
    acc += s * xv;
  }
  frow[256 + d] = f2bf(acc);
}

__global__ void diffuse1_b(const void* __restrict__ dout, size_t offH0,
                           const void* __restrict__ hidden, size_t offH1in,
                           const int* __restrict__ cols, const float* __restrict__ vals,
                           const int* __restrict__ cnt, bf16* __restrict__ feats,
                           const int* __restrict__ flag) {
  int f32 = *flag;
  int bn = blockIdx.x;
  int n = bn & (NN - 1);
  int b = bn >> 10;
  int d = threadIdx.x;
  float x0 = (d < NH) ? loadF(dout, offH0 + (size_t)bn * NH + d, f32)
                      : loadF(hidden, offH1in + (size_t)bn * NH + d - NH, f32);
  float acc = -x0;
  int c = cnt[n];
  for (int j = 0; j < c; ++j) {
    int m = cols[n * MAXNNZ + j];
    float s = vals[n * MAXNNZ + j];
    int bm = (b << 10) | m;
    float x1 = bf2f(feats[(size_t)bm * K1 + 256 + d]);
    acc += 2.f * s * x1;
  }
  feats[(size_t)bn * K1 + 512 + d] = f2bf(acc);
}

// ---- MFMA GEMM: gates(BNx512) = feats(BNxKd) * Bt(512xKd)^T + bias ----
__global__ __launch_bounds__(256) void gemm_bt(const bf16* __restrict__ A,
    const bf16* __restrict__ Bt, const void* __restrict__ bias,
    bf16* __restrict__ C, int Kd, const int* __restrict__ flag) {
  int f32 = *flag;
  __shared__ __align__(16) unsigned short As[128 * 32];
  __shared__ __align__(16) unsigned short Bs[128 * 32];
  const int tid = threadIdx.x;
  const int l = tid & 63;
  const int w = tid >> 6;
  const int wm = w >> 1, wn = w & 1;
  const int m0 = blockIdx.x * 128;
  const int n0 = blockIdx.y * 128;
  const bf16* Ab = A + (size_t)m0 * Kd;
  const bf16* Bb = Bt + (size_t)n0 * Kd;
  const int lr = l & 15, q = l >> 4;
  v4f acc[4][4] = {};
  for (int k0 = 0; k0 < Kd; k0 += 32) {
    v8bf ga[2], gb[2];
#pragma unroll
    for (int t = 0; t < 2; ++t) {
      int s = tid + 256 * t;
      int row = s >> 2, col = (s & 3) * 8;
      ga[t] = *(const v8bf*)(Ab + (size_t)row * Kd + k0 + col);
      gb[t] = *(const v8bf*)(Bb + (size_t)row * Kd + k0 + col);
    }
    __syncthreads();
#pragma unroll
    for (int t = 0; t < 2; ++t) {
      int s = tid + 256 * t;
      int row = s >> 2, col = (s & 3) * 8;
      *(v8bf*)&As[row * 32 + col] = ga[t];
      *(v8bf*)&Bs[row * 32 + col] = gb[t];
    }
    __syncthreads();
    v8bf af[4], bfv[4];
#pragma unroll
    for (int i = 0; i < 4; ++i) {
      af[i]  = *(const v8bf*)&As[(wm * 64 + i * 16 + lr) * 32 + q * 8];
      bfv[i] = *(const v8bf*)&Bs[(wn * 64 + i * 16 + lr) * 32 + q * 8];
    }
#pragma unroll
    for (int mt = 0; mt < 4; ++mt)
#pragma unroll
      for (int nt = 0; nt < 4; ++nt)
        acc[mt][nt] = __builtin_amdgcn_mfma_f32_16x16x32_bf16(af[mt], bfv[nt], acc[mt][nt], 0, 0, 0);
    __syncthreads();
  }
#pragma unroll
  for (int nt = 0; nt < 4; ++nt) {
    int n = n0 + wn * 64 + nt * 16 + lr;
    float bv = loadF(bias, n, f32);
#pragma unroll
    for (int mt = 0; mt < 4; ++mt)
#pragma unroll
      for (int r = 0; r < 4; ++r) {
        int m = m0 + wm * 64 + mt * 16 + q * 4 + r;
        C[(size_t)m * NG + n] = f2bf(acc[mt][nt][r] + bv);
      }
  }
}

// ---- LSTM pointwise ----
__global__ __launch_bounds__(128) void lstm_cell(const bf16* __restrict__ gates,
    const void* __restrict__ cell, size_t offCin, void* __restrict__ dout,
    size_t offH, size_t offC, const int* __restrict__ flag) {
  int f32 = *flag;
  size_t bn = blockIdx.x;
  int h = threadIdx.x;
  const bf16* g = gates + bn * NG;
  float iv = sane(bf2f(g[h]));
  float fv = sane(bf2f(g[NH + h]));
  float ov = sane(bf2f(g[2 * NH + h]));
  float gv = sane(bf2f(g[3 * NH + h]));
  float c = sane(loadF(cell, offCin + bn * NH + h, f32));
  float cn = sigf(fv) * c + sigf(iv) * tanhfast(gv);
  float hn = sigf(ov) * tanhfast(cn);
  storeF(dout, offC + bn * NH + h, cn, f32);
  storeF(dout, offH + bn * NH + h, hn, f32);
}

// ---- fused attention: energy MFMA + softmax + context + projection ----
// Per block: 8 bn-rows. Stage enc[s, bn0..bn0+8, :] for all 12 s as f32 in LDS
// (padded stride 132 floats -> 16B aligned, breaks the 32-bank row conflict),
// plus h1 tile. Energy via 16x16x32 MFMA against L1-resident packed attn_w;
// tanh-dot epilogue -> per-row energies; softmax over s in-LDS; context read
// back from the SAME f32 LDS copy (enc HBM traffic paid exactly once);
// projection dot + wave reduce. 512 threads, ~61 KB LDS -> 2 blocks/CU.
#define AROWS 8
#define EPADF 132
__global__ __launch_bounds__(512) void fused_attn(const void* __restrict__ enc,
    const bf16* __restrict__ BtW, const void* __restrict__ ab,
    void* __restrict__ dout, size_t offH1, size_t offAttn,
    const void* __restrict__ pw, const void* __restrict__ pb,
    const int* __restrict__ flag) {
  int f32 = *flag;
  __shared__ __align__(16) float encsf[(NS * AROWS + 8) * EPADF]; // +8 pad rows for lr>=AROWS frag reads
  __shared__ float h1s[AROWS][NH];
  __shared__ float ered[NS][8][AROWS];
  __shared__ float wts[NS][AROWS];
  const int tid = threadIdx.x;
  const int l = tid & 63, w = tid >> 6;     // 8 waves
  const int bn0 = blockIdx.x * AROWS;

  // zero the pad rows (deterministic garbage for discarded MFMA rows)
  for (int i = tid; i < 8 * EPADF; i += 512) encsf[NS * AROWS * EPADF + i] = 0.f;
  // stage enc slice as f32: 12*8*32 float4 groups
  for (int g = tid; g < NS * AROWS * (NH / 4); g += 512) {
    int s = g >> 8;               // 256 groups per s
    int r = (g >> 5) & 7;
    int cg = g & 31;
    float4 v;
    if (f32) {
      v = *(const float4*)((const float*)enc + ((size_t)s * BN + bn0 + r) * NH + cg * 4);
    } else {
      const bf16* p = (const bf16*)enc + ((size_t)s * BN + bn0 + r) * NH + cg * 4;
      v = make_float4(bf2f(p[0]), bf2f(p[1]), bf2f(p[2]), bf2f(p[3]));
    }
    *(float4*)&encsf[(s * AROWS + r) * EPADF + cg * 4] = v;
  }
  // stage h1 tile (f32)
  for (int i = tid; i < AROWS * NH; i += 512) {
    int r = i >> 7, h = i & 127;
    h1s[r][h] = loadF(dout, offH1 + (size_t)(bn0 + r) * NH + h, f32);
  }
  __syncthreads();

  const int lr = l & 15, q = l >> 4;
  const int n = w * 16 + lr;                // each wave owns 16 energy columns
  const float bvs = loadF(ab, n, f32);
  for (int s = 0; s < NS; ++s) {
    v4f acc = {};
#pragma unroll
    for (int kk = 0; kk < 4; ++kk) {
      const float* ap = &encsf[(s * AROWS + lr) * EPADF + kk * 32 + q * 8];
      float4 a0 = *(const float4*)ap;
      float4 a1 = *(const float4*)(ap + 4);
      union { v8bf v; __hip_bfloat162 h[4]; } ua;
      ua.h[0] = __float22bfloat162_rn(make_float2(a0.x, a0.y));
      ua.h[1] = __float22bfloat162_rn(make_float2(a0.z, a0.w));
      ua.h[2] = __float22bfloat162_rn(make_float2(a1.x, a1.y));
      ua.h[3] = __float22bfloat162_rn(make_float2(a1.z, a1.w));
      v8bf bv = *(const v8bf*)(BtW + (size_t)n * NH + kk * 32 + q * 8);
      acc = __builtin_amdgcn_mfma_f32_16x16x32_bf16(ua.v, bv, acc, 0, 0, 0);
    }
    // epilogue: output row m = q*4+r (only m<AROWS is real), col n
    float parts[4];
#pragma unroll
    for (int r = 0; r < 4; ++r) {
      int m = q * 4 + r;
      float t = tanhfast(acc[r] + bvs);
      parts[r] = (m < AROWS) ? t * h1s[m][n] : 0.f;
    }
#pragma unroll
    for (int r = 0; r < 4; ++r) {
      float v = parts[r];
      v += __shfl_xor(v, 1);
      v += __shfl_xor(v, 2);
      v += __shfl_xor(v, 4);
      v += __shfl_xor(v, 8);
      int m = q * 4 + r;
      if (lr == 0 && m < AROWS) ered[s][w][m] = v;
    }
  }
  __syncthreads();
  // softmax over s per row
  if (tid < AROWS) {
    int m = tid;
    float e[NS];
    float mx = -3.4e38f;
#pragma unroll
    for (int s = 0; s < NS; ++s) {
      float v = 0.f;
#pragma unroll
      for (int ww = 0; ww < 8; ++ww) v += ered[s][ww][m];
      e[s] = sane(v);
      mx = fmaxf(mx, e[s]);
    }
    float sum = 0.f;
#pragma unroll
    for (int s = 0; s < NS; ++s) { e[s] = __expf(e[s] - mx); sum += e[s]; }
    float inv = 1.f / sum;
#pragma unroll
    for (int s = 0; s < NS; ++s) wts[s][m] = e[s] * inv;
  }
  __syncthreads();
  // attention-weights output (B,N,S)
  if (tid < AROWS * NS) {
    int m = tid / NS, s = tid - m * NS;
    storeF(dout, offAttn + (size_t)(bn0 + m) * NS + s, wts[s][m], f32);
  }
  // context + projection: wave w owns row m = w
  {
    int m = w;
    float part = 0.f;
#pragma unroll
    for (int hh = 0; hh < 2; ++hh) {
      int h = l + hh * 64;
      float ctx = 0.f;
#pragma unroll
      for (int s = 0; s < NS; ++s)
        ctx += wts[s][m] * encsf[(s * AROWS + m) * EPADF + h];
      part += sane(h1s[m][h] * loadF(pw, h, f32) + ctx * loadF(pw, NH + h, f32));
    }
#pragma unroll
    for (int mask = 1; mask < 64; mask <<= 1) part += __shfl_xor(part, mask);
    if (l == 0) storeF(dout, bn0 + m, part + loadF(pb, 0, f32), f32);
  }
}

extern "C" void kernel_launch(void* const* d_in, const int* in_sizes, int n_in,
                              void* d_out, int out_size, void* d_ws, size_t ws_size,
                              hipStream_t stream) {
  const void* xin    = d_in[0];
  const void* enc    = d_in[1];
  const void* hidden = d_in[2];
  const void* cell   = d_in[3];
  const void* sup    = d_in[4];
  const void* w0     = d_in[5];
  const void* b0     = d_in[6];
  const void* w1     = d_in[7];
  const void* b1     = d_in[8];
  const void* aw     = d_in[9];
  const void* ab     = d_in[10];
  const void* pw     = d_in[11];
  const void* pb     = d_in[12];

  char* ws = (char*)d_ws;
  size_t off = 0;
  auto alloc = [&](size_t bytes) -> char* {
    char* p = ws + off;
    off += (bytes + 255) & ~(size_t)255;
    return p;
  };
  bf16*  feats    = (bf16*)alloc((size_t)BN * K1 * 2);   // 100 MB (layer0 uses K0P stride)
  bf16*  gates    = (bf16*)alloc((size_t)BN * NG * 2);   // 67 MB
  bf16*  Bt0      = (bf16*)alloc((size_t)NG * K0P * 2);
  bf16*  Bt1      = (bf16*)alloc((size_t)NG * K1 * 2);
  bf16*  BtA      = (bf16*)alloc((size_t)NH * NH * 2);
  int*   csr_cols = (int*)alloc((size_t)NN * MAXNNZ * 4);
  float* csr_vals = (float*)alloc((size_t)NN * MAXNNZ * 4);
  int*   csr_cnt  = (int*)alloc((size_t)NN * 4);
  int*   flag     = (int*)alloc(256);

  const size_t OFF_HS   = (size_t)BN;
  const size_t OFF_CS   = OFF_HS + (size_t)2 * BN * NH;
  const size_t OFF_ATTN = OFF_CS + (size_t)2 * BN * NH;
  const size_t OFF_H0 = OFF_HS;
  const size_t OFF_H1 = OFF_HS + (size_t)BN * NH;
  const size_t OFF_C0 = OFF_CS;
  const size_t OFF_C1 = OFF_CS + (size_t)BN * NH;
  const size_t LAYER1 = (size_t)BN * NH;

  detect_dtype<<<1, 256, 0, stream>>>((const unsigned short*)cell, flag);
  build_csr<<<NN, 256, 0, stream>>>(sup, csr_cols, csr_vals, csr_cnt, flag);
  pack_wt<<<NG, 256, 0, stream>>>(w0, Bt0, 387, K0P, NG, flag);
  pack_wt<<<NG, 256, 0, stream>>>(w1, Bt1, K1, K1, NG, flag);
  pack_wt<<<NH, 128, 0, stream>>>(aw, BtA, NH, NH, NH, flag);

  // layer 0 (single pass over all 65536 rows)
  diffuse0_a<<<BN, 192, 0, stream>>>(xin, hidden, csr_cols, csr_vals, csr_cnt, feats, flag);
  diffuse0_b<<<BN, 192, 0, stream>>>(xin, hidden, csr_cols, csr_vals, csr_cnt, feats, flag);
  {
    dim3 g(BN / 128, NG / 128);
    gemm_bt<<<g, 256, 0, stream>>>(feats, Bt0, b0, gates, K0P, flag);
  }
  lstm_cell<<<BN, 128, 0, stream>>>(gates, cell, 0, d_out, OFF_H0, OFF_C0, flag);

  // layer 1
  diffuse1_a<<<BN, 256, 0, stream>>>(d_out, OFF_H0, hidden, LAYER1,
                                     csr_cols, csr_vals, csr_cnt, feats, flag);
  diffuse1_b<<<BN, 256, 0, stream>>>(d_out, OFF_H0, hidden, LAYER1,
                                     csr_cols, csr_vals, csr_cnt, feats, flag);
  {
    dim3 g(BN / 128, NG / 128);
    gemm_bt<<<g, 256, 0, stream>>>(feats, Bt1, b1, gates, K1, flag);
  }
  lstm_cell<<<BN, 128, 0, stream>>>(gates, cell, LAYER1, d_out, OFF_H1, OFF_C1, flag);

  // attention + softmax + context + projection, single pass over enc
  fused_attn<<<BN / AROWS, 512, 0, stream>>>(enc, BtA, ab, d_out, OFF_H1, OFF_ATTN,
                                             pw, pb, flag);
}

// Round 2
// 1901.003 us; speedup vs baseline: 1.1101x; 1.1101x over previous
//
#include <hip/hip_runtime.h>
#include <hip/hip_bf16.h>
#include <stdint.h>

#define NB 64
#define NN 1024
#define NH 128
#define NS 12
#define BN (NB*NN)
#define D0 129
#define K0P 416
#define K1 768
#define NG 512
#define MAXNNZ 128

typedef __hip_bfloat16 bf16;
typedef float v4f __attribute__((ext_vector_type(4)));
typedef __bf16 v8bf __attribute__((ext_vector_type(8)));

__device__ __forceinline__ float bf2f(bf16 x) { return __bfloat162float(x); }
__device__ __forceinline__ bf16 f2bf(float x) { return __float2bfloat16(x); }
__device__ __forceinline__ float sane(float x) { return __builtin_isfinite(x) ? x : 0.f; }
__device__ __forceinline__ float sigf(float x) { return 1.f / (1.f + __expf(-x)); }
__device__ __forceinline__ float tanhfast(float x) { return 1.f - 2.f / (1.f + __expf(2.f * x)); }

// flagged load/store: f32 ? float data : bf16 data (flag is uniform per launch)
__device__ __forceinline__ float loadF(const void* p, size_t i, int f32) {
  return f32 ? ((const float*)p)[i] : bf2f(((const bf16*)p)[i]);
}
__device__ __forceinline__ void storeF(void* p, size_t i, float v, int f32) {
  if (f32) ((float*)p)[i] = v; else ((bf16*)p)[i] = f2bf(v);
}
// 8 elements -> v8bf; f32 path uses two float4 loads + packed converts
__device__ __forceinline__ v8bf load8(const void* p, size_t i, int f32) {
  if (f32) {
    const float4 a = *(const float4*)((const float*)p + i);
    const float4 b = *(const float4*)((const float*)p + i + 4);
    union { v8bf v; __hip_bfloat162 h[4]; } u;
    u.h[0] = __float22bfloat162_rn(make_float2(a.x, a.y));
    u.h[1] = __float22bfloat162_rn(make_float2(a.z, a.w));
    u.h[2] = __float22bfloat162_rn(make_float2(b.x, b.y));
    u.h[3] = __float22bfloat162_rn(make_float2(b.z, b.w));
    return u.v;
  }
  return *(const v8bf*)((const bf16*)p + i);
}

// dtype detector on ~N(0,1) probe: bf16 data -> even uint16s are real bf16
// (exponent 117..131 or zero); f32 data -> even uint16s are mantissa halves.
__global__ void detect_dtype(const unsigned short* __restrict__ probe, int* __restrict__ flag) {
  int t = threadIdx.x;
  unsigned short x = probe[2 * t];
  int e = (x >> 7) & 0xFF;
  int insane = !((x & 0x7FFF) == 0 || (e >= 117 && e <= 131));
  __shared__ int cnt;
  if (t == 0) cnt = 0;
  __syncthreads();
  atomicAdd(&cnt, insane);
  __syncthreads();
  if (t == 0) *flag = (cnt > 64) ? 1 : 0;
}

__global__ void build_csr(const void* __restrict__ sup, int* __restrict__ cols,
                          float* __restrict__ vals, int* __restrict__ cnt,
                          const int* __restrict__ flag) {
  int f32 = *flag;
  int n = blockIdx.x;
  __shared__ int cn;
  if (threadIdx.x == 0) cn = 0;
  __syncthreads();
  for (int m = threadIdx.x; m < NN; m += blockDim.x) {
    float v = loadF(sup, (size_t)n * NN + m, f32);
    if (v != 0.0f && __builtin_isfinite(v)) {
      int slot = atomicAdd(&cn, 1);
      if (slot < MAXNNZ) { cols[n * MAXNNZ + slot] = m; vals[n * MAXNNZ + slot] = v; }
    }
  }
  __syncthreads();
  if (threadIdx.x == 0) cnt[n] = (cn < MAXNNZ) ? cn : MAXNNZ;
}

__global__ void pack_wt(const void* __restrict__ w, bf16* __restrict__ bt,
                        int K, int Kp, int Nn, const int* __restrict__ flag) {
  int f32 = *flag;
  int n = blockIdx.x;
  for (int k = threadIdx.x; k < Kp; k += blockDim.x) {
    float v = (k < K) ? loadF(w, (size_t)k * Nn + n, f32) : 0.0f;
    bt[(size_t)n * Kp + k] = f2bf(v);
  }
}

// ---- layer 0 diffusion ----
__global__ void diffuse0_a(const void* __restrict__ xin, const void* __restrict__ h0,
                           const int* __restrict__ cols, const float* __restrict__ vals,
                           const int* __restrict__ cnt, bf16* __restrict__ feats,
                           const int* __restrict__ flag) {
  int f32 = *flag;
  int bn = blockIdx.x;
  int n = bn & (NN - 1);
  int b = bn >> 10;
  int d = threadIdx.x;
  bf16* frow = feats + (size_t)bn * K0P;
  if (d < D0) {
    float x0 = (d == 0) ? loadF(xin, bn, f32) : loadF(h0, (size_t)bn * NH + d - 1, f32);
    frow[d] = f2bf(x0);
    float acc = 0.f;
    int c = cnt[n];
    for (int j = 0; j < c; ++j) {
      int m = cols[n * MAXNNZ + j];
      float s = vals[n * MAXNNZ + j];
      int bm = (b << 10) | m;
      float xv = (d == 0) ? loadF(xin, bm, f32) : loadF(h0, (size_t)bm * NH + d - 1, f32);
      acc += s * xv;
    }
    frow[D0 + d] = f2bf(acc);
  } else if (d < D0 + (K0P - 3 * D0)) {
    frow[3 * D0 + (d - D0)] = f2bf(0.f);
  }
}

__global__ void diffuse0_b(const void* __restrict__ xin, const void* __restrict__ h0,
                           const int* __restrict__ cols, const float* __restrict__ vals,
                           const int* __restrict__ cnt, bf16* __restrict__ feats,
                           const int* __restrict__ flag) {
  int f32 = *flag;
  int bn = blockIdx.x;
  int n = bn & (NN - 1);
  int b = bn >> 10;
  int d = threadIdx.x;
  if (d >= D0) return;
  float x0 = (d == 0) ? loadF(xin, bn, f32) : loadF(h0, (size_t)bn * NH + d - 1, f32);
  float acc = -x0;
  int c = cnt[n];
  for (int j = 0; j < c; ++j) {
    int m = cols[n * MAXNNZ + j];
    float s = vals[n * MAXNNZ + j];
    int bm = (b << 10) | m;
    float x1 = bf2f(feats[(size_t)bm * K0P + D0 + d]);
    acc += 2.f * s * x1;
  }
  feats[(size_t)bn * K0P + 2 * D0 + d] = f2bf(acc);
}

// ---- layer 1 diffusion ----
__global__ void diffuse1_a(const void* __restrict__ dout, size_t offH0,
                           const void* __restrict__ hidden, size_t offH1in,
                           const int* __restrict__ cols, const float* __restrict__ vals,
                           const int* __restrict__ cnt, bf16* __restrict__ feats,
                           const int* __restrict__ flag) {
  int f32 = *flag;
  int bn = blockIdx.x;
  int n = bn & (NN - 1);
  int b = bn >> 10;
  int d = threadIdx.x;   // 0..255
  bf16* frow = feats + (size_t)bn * K1;
  float x0 = (d < NH) ? loadF(dout, offH0 + (size_t)bn * NH + d, f32)
                      : loadF(hidden, offH1in + (size_t)bn * NH + d - NH, f32);
  frow[d] = f2bf(x0);
  float acc = 0.f;
  int c = cnt[n];
  for (int j = 0; j < c; ++j) {
    int m = cols[n * MAXNNZ + j];
    float s = vals[n * MAXNNZ + j];
    size_t bm = (size_t)((b << 10) | m) * NH;
    float xv = (d < NH) ? loadF(dout, offH0 + bm + d, f32)
                        : loadF(hidden, offH1in + bm + d - NH, f32);
    acc += s * xv;
  }
  frow[256 + d] = f2bf(acc);
}

__global__ void diffuse1_b(const void* __restrict__ dout, size_t offH0,
                           const void* __restrict__ hidden, size_t offH1in,
                           const int* __restrict__ cols, const float* __restrict__ vals,
                           const int* __restrict__ cnt, bf16* __restrict__ feats,
                           const int* __restrict__ flag) {
  int f32 = *flag;
  int bn = blockIdx.x;
  int n = bn & (NN - 1);
  int b = bn >> 10;
  int d = threadIdx.x;
  float x0 = (d < NH) ? loadF(dout, offH0 + (size_t)bn * NH + d, f32)
                      : loadF(hidden, offH1in + (size_t)bn * NH + d - NH, f32);
  float acc = -x0;
  int c = cnt[n];
  for (int j = 0; j < c; ++j) {
    int m = cols[n * MAXNNZ + j];
    float s = vals[n * MAXNNZ + j];
    int bm = (b << 10) | m;
    float x1 = bf2f(feats[(size_t)bm * K1 + 256 + d]);
    acc += 2.f * s * x1;
  }
  feats[(size_t)bn * K1 + 512 + d] = f2bf(acc);
}

// ---- MFMA GEMM: gates(BNx512) = feats(BNxKd) * Bt(512xKd)^T + bias ----
__global__ __launch_bounds__(256) void gemm_bt(const bf16* __restrict__ A,
    const bf16* __restrict__ Bt, const void* __restrict__ bias,
    bf16* __restrict__ C, int Kd, const int* __restrict__ flag) {
  int f32 = *flag;
  __shared__ __align__(16) unsigned short As[128 * 32];
  __shared__ __align__(16) unsigned short Bs[128 * 32];
  const int tid = threadIdx.x;
  const int l = tid & 63;
  const int w = tid >> 6;
  const int wm = w >> 1, wn = w & 1;
  const int m0 = blockIdx.x * 128;
  const int n0 = blockIdx.y * 128;
  const bf16* Ab = A + (size_t)m0 * Kd;
  const bf16* Bb = Bt + (size_t)n0 * Kd;
  const int lr = l & 15, q = l >> 4;
  v4f acc[4][4] = {};
  for (int k0 = 0; k0 < Kd; k0 += 32) {
    v8bf ga[2], gb[2];
#pragma unroll
    for (int t = 0; t < 2; ++t) {
      int s = tid + 256 * t;
      int row = s >> 2, col = (s & 3) * 8;
      ga[t] = *(const v8bf*)(Ab + (size_t)row * Kd + k0 + col);
      gb[t] = *(const v8bf*)(Bb + (size_t)row * Kd + k0 + col);
    }
    __syncthreads();
#pragma unroll
    for (int t = 0; t < 2; ++t) {
      int s = tid + 256 * t;
      int row = s >> 2, col = (s & 3) * 8;
      *(v8bf*)&As[row * 32 + col] = ga[t];
      *(v8bf*)&Bs[row * 32 + col] = gb[t];
    }
    __syncthreads();
    v8bf af[4], bfv[4];
#pragma unroll
    for (int i = 0; i < 4; ++i) {
      af[i]  = *(const v8bf*)&As[(wm * 64 + i * 16 + lr) * 32 + q * 8];
      bfv[i] = *(const v8bf*)&Bs[(wn * 64 + i * 16 + lr) * 32 + q * 8];
    }
#pragma unroll
    for (int mt = 0; mt < 4; ++mt)
#pragma unroll
      for (int nt = 0; nt < 4; ++nt)
        acc[mt][nt] = __builtin_amdgcn_mfma_f32_16x16x32_bf16(af[mt], bfv[nt], acc[mt][nt], 0, 0, 0);
    __syncthreads();
  }
#pragma unroll
  for (int nt = 0; nt < 4; ++nt) {
    int n = n0 + wn * 64 + nt * 16 + lr;
    float bv = loadF(bias, n, f32);
#pragma unroll
    for (int mt = 0; mt < 4; ++mt)
#pragma unroll
      for (int r = 0; r < 4; ++r) {
        int m = m0 + wm * 64 + mt * 16 + q * 4 + r;
        C[(size_t)m * NG + n] = f2bf(acc[mt][nt][r] + bv);
      }
  }
}

// ---- LSTM pointwise ----
__global__ __launch_bounds__(128) void lstm_cell(const bf16* __restrict__ gates,
    const void* __restrict__ cell, size_t offCin, void* __restrict__ dout,
    size_t offH, size_t offC, const int* __restrict__ flag) {
  int f32 = *flag;
  size_t bn = blockIdx.x;
  int h = threadIdx.x;
  const bf16* g = gates + bn * NG;
  float iv = sane(bf2f(g[h]));
  float fv = sane(bf2f(g[NH + h]));
  float ov = sane(bf2f(g[2 * NH + h]));
  float gv = sane(bf2f(g[3 * NH + h]));
  float c = sane(loadF(cell, offCin + bn * NH + h, f32));
  float cn = sigf(fv) * c + sigf(iv) * tanhfast(gv);
  float hn = sigf(ov) * tanhfast(cn);
  storeF(dout, offC + bn * NH + h, cn, f32);
  storeF(dout, offH + bn * NH + h, hn, f32);
}

// ---- flash attention: per block 128 bn-rows, loop s=0..11 with online softmax ----
// enc[s, bn0:bn0+128, :] staged once per s as bf16 LDS tile (read from HBM exactly
// once); energy via proven 128x128 MFMA geometry vs LDS-resident packed attn_w;
// tanh-dot epilogue; online-softmax rescale; ctx accumulated in registers from
// the hot LDS tile. 512 thr (8 waves 2x4), ~76 KB LDS -> 2 blocks/CU.
#define FPAD 132
__global__ __launch_bounds__(512, 4) void flash_attn(const void* __restrict__ enc,
    const bf16* __restrict__ BtW, const void* __restrict__ ab,
    void* __restrict__ dout, size_t offH1, size_t offAttn,
    const void* __restrict__ pw, const void* __restrict__ pb,
    const int* __restrict__ flag) {
  int f32 = *flag;
  __shared__ __align__(16) unsigned short Ws[128 * FPAD];
  __shared__ __align__(16) unsigned short Es[128 * FPAD];
  __shared__ float ered[4][128];
  __shared__ float eall[NS][128];
  __shared__ float mxs[128], sms[128], psl[128], all[128];
  const int tid = threadIdx.x;
  const int l = tid & 63, w = tid >> 6;      // 8 waves
  const int wm = w >> 2, wn = w & 3;         // 2 x 4
  const int lr = l & 15, q = l >> 4;
  const int bn0 = blockIdx.x * 128;

  // stage packed attn_w (n-major, 128x128 bf16) once
  for (int i = tid; i < 128 * 16; i += 512) {
    int row = i >> 4, c = i & 15;
    *(v8bf*)&Ws[row * FPAD + c * 8] = *(const v8bf*)(BtW + (size_t)row * NH + c * 8);
  }
  if (tid < 128) { mxs[tid] = -3.4e38f; sms[tid] = 0.f; }

  float ctx[32];
#pragma unroll
  for (int j = 0; j < 32; ++j) ctx[j] = 0.f;
  const int cm = tid >> 2;            // ctx row (4 threads per row)
  const int ch0 = (tid & 3) * 32;     // ctx col base

  float abv[2];
#pragma unroll
  for (int nt = 0; nt < 2; ++nt) abv[nt] = loadF(ab, wn * 32 + nt * 16 + lr, f32);

  for (int s = 0; s < NS; ++s) {
    __syncthreads();   // prev-iter ctx reads of Es done; Ws staged (covers s=0)
    // stage enc_s tile: contiguous 128x128 slice
#pragma unroll
    for (int t = 0; t < 4; ++t) {
      int idx = tid + 512 * t;
      int row = idx >> 4, c = idx & 15;
      *(v8bf*)&Es[row * FPAD + c * 8] = load8(enc, ((size_t)s * BN + bn0 + row) * NH + c * 8, f32);
    }
    __syncthreads();
    // energy MFMA: E = enc_s @ attn_w (128x128, K=128)
    v4f acc[4][2] = {};
    for (int k0 = 0; k0 < NH; k0 += 32) {
      v8bf af[4], bv[2];
#pragma unroll
      for (int mt = 0; mt < 4; ++mt)
        af[mt] = *(const v8bf*)&Es[(wm * 64 + mt * 16 + lr) * FPAD + k0 + q * 8];
#pragma unroll
      for (int nt = 0; nt < 2; ++nt)
        bv[nt] = *(const v8bf*)&Ws[(wn * 32 + nt * 16 + lr) * FPAD + k0 + q * 8];
#pragma unroll
      for (int mt = 0; mt < 4; ++mt)
#pragma unroll
        for (int nt = 0; nt < 2; ++nt)
          acc[mt][nt] = __builtin_amdgcn_mfma_f32_16x16x32_bf16(af[mt], bv[nt], acc[mt][nt], 0, 0, 0);
    }
    // epilogue: energy[m] = sum_n tanh(E+b) * h1[m,n]; h1 loads L1-hit after s=0
#pragma unroll
    for (int mt = 0; mt < 4; ++mt) {
      float parts[4] = {0.f, 0.f, 0.f, 0.f};
#pragma unroll
      for (int nt = 0; nt < 2; ++nt) {
        int n = wn * 32 + nt * 16 + lr;
#pragma unroll
        for (int r = 0; r < 4; ++r) {
          int m = wm * 64 + mt * 16 + q * 4 + r;
          float t = tanhfast(acc[mt][nt][r] + abv[nt]);
          parts[r] += t * loadF(dout, offH1 + (size_t)(bn0 + m) * NH + n, f32);
        }
      }
#pragma unroll
      for (int r = 0; r < 4; ++r) {
        float v = parts[r];
        v += __shfl_xor(v, 1);
        v += __shfl_xor(v, 2);
        v += __shfl_xor(v, 4);
        v += __shfl_xor(v, 8);
        if (lr == 0) ered[wn][wm * 64 + mt * 16 + q * 4 + r] = v;
      }
    }
    __syncthreads();
    // online-softmax update (one thread per row)
    if (tid < 128) {
      float e = sane(ered[0][tid] + ered[1][tid] + ered[2][tid] + ered[3][tid]);
      eall[s][tid] = e;
      float mo = mxs[tid];
      float mn = fmaxf(mo, e);
      float a = __expf(mo - mn);
      float p = __expf(e - mn);
      sms[tid] = sms[tid] * a + p;
      mxs[tid] = mn;
      all[tid] = a;
      psl[tid] = p;
    }
    __syncthreads();
    // ctx update from the still-hot LDS tile
    {
      float a = all[cm], p = psl[cm];
      const unsigned short* ep = &Es[cm * FPAD + ch0];
#pragma unroll
      for (int j = 0; j < 32; ++j)
        ctx[j] = ctx[j] * a + p * __uint_as_float((unsigned)ep[j] << 16);
    }
  }
  __syncthreads();
  // final weights + store; reuse all[] as inv-sum
  if (tid < 128) {
    float inv = 1.f / sms[tid];
    all[tid] = inv;
    float mxf = mxs[tid];
#pragma unroll
    for (int s = 0; s < NS; ++s) {
      float wv = __expf(eall[s][tid] - mxf) * inv;
      storeF(dout, offAttn + (size_t)(bn0 + tid) * NS + s, wv, f32);
    }
  }
  __syncthreads();
  // projection: out[bn] = sum_h h1*pw[h] + (ctx/sum)*pw[NH+h] + pb
  {
    float inv = all[cm];
    float part = 0.f;
#pragma unroll
    for (int j = 0; j < 32; ++j) {
      int h = ch0 + j;
      float hv = loadF(dout, offH1 + (size_t)(bn0 + cm) * NH + h, f32);
      part += hv * loadF(pw, h, f32) + ctx[j] * inv * loadF(pw, NH + h, f32);
    }
    part = sane(part);
    part += __shfl_xor(part, 1);
    part += __shfl_xor(part, 2);
    if ((tid & 3) == 0) storeF(dout, bn0 + cm, part + loadF(pb, 0, f32), f32);
  }
}

extern "C" void kernel_launch(void* const* d_in, const int* in_sizes, int n_in,
                              void* d_out, int out_size, void* d_ws, size_t ws_size,
                              hipStream_t stream) {
  const void* xin    = d_in[0];
  const void* enc    = d_in[1];
  const void* hidden = d_in[2];
  const void* cell   = d_in[3];
  const void* sup    = d_in[4];
  const void* w0     = d_in[5];
  const void* b0     = d_in[6];
  const void* w1     = d_in[7];
  const void* b1     = d_in[8];
  const void* aw     = d_in[9];
  const void* ab     = d_in[10];
  const void* pw     = d_in[11];
  const void* pb     = d_in[12];

  char* ws = (char*)d_ws;
  size_t off = 0;
  auto alloc = [&](size_t bytes) -> char* {
    char* p = ws + off;
    off += (bytes + 255) & ~(size_t)255;
    return p;
  };
  bf16*  feats    = (bf16*)alloc((size_t)BN * K1 * 2);
  bf16*  gates    = (bf16*)alloc((size_t)BN * NG * 2);
  bf16*  Bt0      = (bf16*)alloc((size_t)NG * K0P * 2);
  bf16*  Bt1      = (bf16*)alloc((size_t)NG * K1 * 2);
  bf16*  BtA      = (bf16*)alloc((size_t)NH * NH * 2);
  int*   csr_cols = (int*)alloc((size_t)NN * MAXNNZ * 4);
  float* csr_vals = (float*)alloc((size_t)NN * MAXNNZ * 4);
  int*   csr_cnt  = (int*)alloc((size_t)NN * 4);
  int*   flag     = (int*)alloc(256);

  const size_t OFF_HS   = (size_t)BN;
  const size_t OFF_CS   = OFF_HS + (size_t)2 * BN * NH;
  const size_t OFF_ATTN = OFF_CS + (size_t)2 * BN * NH;
  const size_t OFF_H0 = OFF_HS;
  const size_t OFF_H1 = OFF_HS + (size_t)BN * NH;
  const size_t OFF_C0 = OFF_CS;
  const size_t OFF_C1 = OFF_CS + (size_t)BN * NH;
  const size_t LAYER1 = (size_t)BN * NH;

  detect_dtype<<<1, 256, 0, stream>>>((const unsigned short*)cell, flag);
  build_csr<<<NN, 256, 0, stream>>>(sup, csr_cols, csr_vals, csr_cnt, flag);
  pack_wt<<<NG, 256, 0, stream>>>(w0, Bt0, 387, K0P, NG, flag);
  pack_wt<<<NG, 256, 0, stream>>>(w1, Bt1, K1, K1, NG, flag);
  pack_wt<<<NH, 128, 0, stream>>>(aw, BtA, NH, NH, NH, flag);

  // layer 0
  diffuse0_a<<<BN, 192, 0, stream>>>(xin, hidden, csr_cols, csr_vals, csr_cnt, feats, flag);
  diffuse0_b<<<BN, 192, 0, stream>>>(xin, hidden, csr_cols, csr_vals, csr_cnt, feats, flag);
  {
    dim3 g(BN / 128, NG / 128);
    gemm_bt<<<g, 256, 0, stream>>>(feats, Bt0, b0, gates, K0P, flag);
  }
  lstm_cell<<<BN, 128, 0, stream>>>(gates, cell, 0, d_out, OFF_H0, OFF_C0, flag);

  // layer 1
  diffuse1_a<<<BN, 256, 0, stream>>>(d_out, OFF_H0, hidden, LAYER1,
                                     csr_cols, csr_vals, csr_cnt, feats, flag);
  diffuse1_b<<<BN, 256, 0, stream>>>(d_out, OFF_H0, hidden, LAYER1,
                                     csr_cols, csr_vals, csr_cnt, feats, flag);
  {
    dim3 g(BN / 128, NG / 128);
    gemm_bt<<<g, 256, 0, stream>>>(feats, Bt1, b1, gates, K1, flag);
  }
  lstm_cell<<<BN, 128, 0, stream>>>(gates, cell, LAYER1, d_out, OFF_H1, OFF_C1, flag);

  // fused attention: enc read from HBM exactly once
  flash_attn<<<BN / 128, 512, 0, stream>>>(enc, BtA, ab, d_out, OFF_H1, OFF_ATTN,
                                           pw, pb, flag);
}